// Round 26
// baseline (851.708 us; speedup 1.0000x reference)
//
#include <hip/hip_runtime.h>

// AWQ fused dequant + GEMM, MI355X -- R26: OUTPUT IS FLOAT32 (solved R25).
//   x: fp32 [M,K]-C (fp16 upcast) | q: int32 [N,K]-C, [0,16) | s,z: fp32 [G,N]-C
//   bias: fp32 [N] | out: FLOAT32 [M,N]-C.
// Channel proof: even-uint16 sentinels invisible (low half of fp32), odd
// visible (high half); dense bf16 writes = position-shifted garbage ->
// explains every prior 126-155 err. Structure: R2/R4-validated 128x128x64
// MFMA tile, reg-staged LDS, 4 waves, bf16 MFMA with fp32 accum.

typedef __attribute__((ext_vector_type(8))) __bf16 bf16x8;
typedef __attribute__((ext_vector_type(4))) float f32x4;

#define BM 128
#define BN 128
#define BK 64
#define NTHREADS 256

__device__ __forceinline__ unsigned short f_to_bf16(float f) {
  union { float f; unsigned int i; } c; c.f = f;
  unsigned int u = c.i;
  u += 0x7fffu + ((u >> 16) & 1u);   // RNE (finite)
  return (unsigned short)(u >> 16);
}

__global__ __launch_bounds__(NTHREADS, 2)
void awq_gemm_kernel(const float* __restrict__ X,
                     const int* __restrict__ Q,
                     const float* __restrict__ S,
                     const float* __restrict__ Z,
                     const float* __restrict__ Bias,
                     float* __restrict__ Out,
                     int M, int N, int K, int GS)
{
  __shared__ unsigned short As[BM * BK];   // x tile bf16 [m][k]
  __shared__ unsigned short Bs[BN * BK];   // dequant weight tile bf16 [n][k]

  const int tid  = threadIdx.x;
  const int wave = tid >> 6;
  const int lane = tid & 63;

  const int mtiles = M / BM;
  const int mt = blockIdx.x % mtiles;      // mtile fastest -> weight-panel L2 reuse
  const int nt = blockIdx.x / mtiles;
  const int m0 = mt * BM;
  const int n0 = nt * BN;

  const int wm = (wave >> 1) * 64;         // 2x2 wave grid, 64x64 per wave
  const int wn = (wave & 1) * 64;

  f32x4 acc[4][4];
#pragma unroll
  for (int i = 0; i < 4; ++i)
#pragma unroll
    for (int j = 0; j < 4; ++j)
      acc[i][j] = (f32x4){0.f, 0.f, 0.f, 0.f};

  const int bn_row = tid >> 4;             // 0..15
  const int bk_col = (tid & 15) * 4;       // 0..60

  const int ksteps = K / BK;
  for (int kt = 0; kt < ksteps; ++kt) {
    const int k0 = kt * BK;
    const int g  = k0 / GS;                // constant across BK tile (BK <= GS)

    // ---- stage A tile (fp32 -> bf16) into regs
    ushort4 sv[8];
    {
      const float* Xf = X + (size_t)m0 * K + k0;
#pragma unroll
      for (int it = 0; it < 8; ++it) {
        const int elem = it * 1024 + tid * 4;          // 8192 elems
        const int row = elem >> 6, col = elem & 63;
        const float4 v = *reinterpret_cast<const float4*>(Xf + (size_t)row * K + col);
        sv[it].x = f_to_bf16(v.x); sv[it].y = f_to_bf16(v.y);
        sv[it].z = f_to_bf16(v.z); sv[it].w = f_to_bf16(v.w);
      }
    }

    // ---- load Q + dequant to bf16 in regs (s/z [G,N]-C: addr g*N + n)
    ushort4 w4[8];
#pragma unroll
    for (int it = 0; it < 8; ++it) {
      const int n = it * 16 + bn_row;
      const int4 qv = *reinterpret_cast<const int4*>(
          Q + (size_t)(n0 + n) * K + k0 + bk_col);
      const float sf = S[(size_t)g * N + n0 + n];
      const float zf = Z[(size_t)g * N + n0 + n];
      w4[it].x = f_to_bf16((float)qv.x * sf + zf);
      w4[it].y = f_to_bf16((float)qv.y * sf + zf);
      w4[it].z = f_to_bf16((float)qv.z * sf + zf);
      w4[it].w = f_to_bf16((float)qv.w * sf + zf);
    }

    __syncthreads();                       // previous tile fully consumed

#pragma unroll
    for (int it = 0; it < 8; ++it) {
      const int elem = it * 1024 + tid * 4;
      *reinterpret_cast<ushort4*>(&As[elem]) = sv[it];
    }
#pragma unroll
    for (int it = 0; it < 8; ++it) {
      const int n = it * 16 + bn_row;
      *reinterpret_cast<ushort4*>(&Bs[n * BK + bk_col]) = w4[it];
    }

    __syncthreads();                       // staging visible

    // ---- MFMA inner loop: 2 k-subtiles of 32, 4x4 fragments per wave
#pragma unroll
    for (int kk = 0; kk < 2; ++kk) {
      const int klane = kk * 32 + (lane >> 4) * 8;
      bf16x8 a[4], b[4];
#pragma unroll
      for (int i = 0; i < 4; ++i)
        a[i] = *reinterpret_cast<const bf16x8*>(
            &As[(wm + i * 16 + (lane & 15)) * BK + klane]);
#pragma unroll
      for (int j = 0; j < 4; ++j)
        b[j] = *reinterpret_cast<const bf16x8*>(
            &Bs[(wn + j * 16 + (lane & 15)) * BK + klane]);
#pragma unroll
      for (int i = 0; i < 4; ++i)
#pragma unroll
        for (int j = 0; j < 4; ++j)
          acc[i][j] = __builtin_amdgcn_mfma_f32_16x16x32_bf16(a[i], b[j], acc[i][j], 0, 0, 0);
    }
  }

  // ---- Epilogue: acc + bias -> FLOAT32 out
  // C/D layout (16x16x32): col(N)=lane&15, row(M)=(lane>>4)*4+r  [m89/m91]
  const int colbase = n0 + wn + (lane & 15);
  const int rowbase = m0 + wm + ((lane >> 4) << 2);
#pragma unroll
  for (int j = 0; j < 4; ++j) {
    const int col = colbase + j * 16;
    const float bv = Bias[col];
#pragma unroll
    for (int i = 0; i < 4; ++i) {
      const int row = rowbase + i * 16;
#pragma unroll
      for (int r = 0; r < 4; ++r) {
        Out[(size_t)(row + r) * N + col] = acc[i][j][r] + bv;
      }
    }
  }
}

extern "C" void kernel_launch(void* const* d_in, const int* in_sizes, int n_in,
                              void* d_out, int out_size, void* d_ws, size_t ws_size,
                              hipStream_t stream) {
  const float* x    = (const float*)d_in[0];
  const int*   q    = (const int*)d_in[1];
  const float* s    = (const float*)d_in[2];
  const float* z    = (const float*)d_in[3];
  const float* bias = (const float*)d_in[4];
  float*       out  = (float*)d_out;

  const int N  = in_sizes[4];              // 11008
  const int K  = in_sizes[1] / N;          // 4096
  const int M  = in_sizes[0] / K;          // 2048
  const int G  = in_sizes[2] / N;          // 32
  const int GS = K / G;                    // 128

  const int grid = (M / BM) * (N / BN);    // 16 * 86 = 1376
  awq_gemm_kernel<<<grid, NTHREADS, 0, stream>>>(x, q, s, z, bias, out, M, N, K, GS);
}

// Round 27
// 433.611 us; speedup vs baseline: 1.9642x; 1.9642x over previous
//
#include <hip/hip_runtime.h>

// AWQ fused dequant + GEMM, MI355X -- R27: perf round 1.
// Conventions (R26-verified PASS): x fp32 [M,K]-C, q int32 [N,K]-C [0,16),
// s/z fp32 [G,N]-C, bias fp32 [N], out FP32 [M,N]-C.
// Changes vs R26 (851us, MfmaUtil 7.7%, 6.8e7 bank conflicts):
//  T2: LDS XOR swizzle (col ^= (row&7)<<3 ushorts) on As/Bs write+read --
//      kills the 16-way ds_read_b128 conflict ([row][64] = 128B row stride).
//  T3-min: q/s/z prefetched into regs across the MFMA phase (cold-data
//      latency hidden under MFMA); A loads overlap dequant VALU.
//  T1: bijective XCD chunk swizzle (grid 1376 = 8*172), mt-fastest within
//      chunk -> weight panel (2MB) reused within one XCD L2.

typedef __attribute__((ext_vector_type(8))) __bf16 bf16x8;
typedef __attribute__((ext_vector_type(4))) float f32x4;

#define BM 128
#define BN 128
#define BK 64
#define NTHREADS 256
#define NXCD 8

__device__ __forceinline__ unsigned short f_to_bf16(float f) {
  union { float f; unsigned int i; } c; c.f = f;
  unsigned int u = c.i;
  u += 0x7fffu + ((u >> 16) & 1u);   // RNE (finite)
  return (unsigned short)(u >> 16);
}

__global__ __launch_bounds__(NTHREADS, 2)
void awq_gemm_kernel(const float* __restrict__ X,
                     const int* __restrict__ Q,
                     const float* __restrict__ S,
                     const float* __restrict__ Z,
                     const float* __restrict__ Bias,
                     float* __restrict__ Out,
                     int M, int N, int K, int GS)
{
  __shared__ unsigned short As[BM * BK];   // x tile bf16, XOR-swizzled
  __shared__ unsigned short Bs[BN * BK];   // weight tile bf16, XOR-swizzled

  const int tid  = threadIdx.x;
  const int wave = tid >> 6;
  const int lane = tid & 63;

  // ---- XCD-aware bijective block swizzle (T1)
  const int nwg = gridDim.x;
  int bid = blockIdx.x;
  if ((nwg % NXCD) == 0) {
    const int cpx = nwg / NXCD;
    bid = (blockIdx.x % NXCD) * cpx + blockIdx.x / NXCD;
  }
  const int mtiles = M / BM;
  const int mt = bid % mtiles;             // mt fastest -> panel reuse in-XCD
  const int nt = bid / mtiles;
  const int m0 = mt * BM;
  const int n0 = nt * BN;

  const int wm = (wave >> 1) * 64;         // 2x2 wave grid, 64x64 per wave
  const int wn = (wave & 1) * 64;

  f32x4 acc[4][4];
#pragma unroll
  for (int i = 0; i < 4; ++i)
#pragma unroll
    for (int j = 0; j < 4; ++j)
      acc[i][j] = (f32x4){0.f, 0.f, 0.f, 0.f};

  const int bn_row = tid >> 4;             // 0..15
  const int bk_col = (tid & 15) * 4;       // 0..60

  const int ksteps = K / BK;

  // ---- prologue: prefetch q/s/z for kt = 0
  int4  qv[8];
  float sf[8], zf[8];
#pragma unroll
  for (int it = 0; it < 8; ++it) {
    const int n = it * 16 + bn_row;
    qv[it] = *reinterpret_cast<const int4*>(Q + (size_t)(n0 + n) * K + bk_col);
    sf[it] = S[(size_t)0 * N + n0 + n];
    zf[it] = Z[(size_t)0 * N + n0 + n];
  }

  for (int kt = 0; kt < ksteps; ++kt) {
    const int k0 = kt * BK;

    __syncthreads();                       // prev tile fully consumed

    // ---- issue A loads (latency hidden under dequant VALU below)
    const float* Xf = X + (size_t)m0 * K + k0;
    float4 av[8];
#pragma unroll
    for (int it = 0; it < 8; ++it) {
      const int elem = it * 1024 + tid * 4;
      av[it] = *reinterpret_cast<const float4*>(
          Xf + (size_t)(elem >> 6) * K + (elem & 63));
    }

    // ---- dequant B from prefetched regs (no vmcnt wait) + swizzled write
#pragma unroll
    for (int it = 0; it < 8; ++it) {
      const int n = it * 16 + bn_row;
      ushort4 w;
      w.x = f_to_bf16((float)qv[it].x * sf[it] + zf[it]);
      w.y = f_to_bf16((float)qv[it].y * sf[it] + zf[it]);
      w.z = f_to_bf16((float)qv[it].z * sf[it] + zf[it]);
      w.w = f_to_bf16((float)qv[it].w * sf[it] + zf[it]);
      *reinterpret_cast<ushort4*>(
          &Bs[n * BK + (bk_col ^ ((n & 7) << 3))]) = w;
    }

    // ---- convert + swizzled write A (vmcnt waits amortized across 8)
#pragma unroll
    for (int it = 0; it < 8; ++it) {
      const int elem = it * 1024 + tid * 4;
      const int row = elem >> 6, col = elem & 63;
      ushort4 w;
      w.x = f_to_bf16(av[it].x); w.y = f_to_bf16(av[it].y);
      w.z = f_to_bf16(av[it].z); w.w = f_to_bf16(av[it].w);
      *reinterpret_cast<ushort4*>(
          &As[row * BK + (col ^ ((row & 7) << 3))]) = w;
    }

    __syncthreads();                       // staging visible

    // ---- prefetch q/s/z for kt+1 (completes under MFMA)
    if (kt + 1 < ksteps) {
      const int k0n = k0 + BK;
      const int gn  = k0n / GS;
#pragma unroll
      for (int it = 0; it < 8; ++it) {
        const int n = it * 16 + bn_row;
        qv[it] = *reinterpret_cast<const int4*>(
            Q + (size_t)(n0 + n) * K + k0n + bk_col);
        sf[it] = S[(size_t)gn * N + n0 + n];
        zf[it] = Z[(size_t)gn * N + n0 + n];
      }
    }

    // ---- MFMA inner loop, swizzled ds_read_b128 (2-way conflict = free)
#pragma unroll
    for (int kk = 0; kk < 2; ++kk) {
      const int klane = kk * 32 + (lane >> 4) * 8;
      bf16x8 a[4], b[4];
#pragma unroll
      for (int i = 0; i < 4; ++i) {
        const int row = wm + i * 16 + (lane & 15);
        a[i] = *reinterpret_cast<const bf16x8*>(
            &As[row * BK + (klane ^ ((row & 7) << 3))]);
      }
#pragma unroll
      for (int j = 0; j < 4; ++j) {
        const int row = wn + j * 16 + (lane & 15);
        b[j] = *reinterpret_cast<const bf16x8*>(
            &Bs[row * BK + (klane ^ ((row & 7) << 3))]);
      }
#pragma unroll
      for (int i = 0; i < 4; ++i)
#pragma unroll
        for (int j = 0; j < 4; ++j)
          acc[i][j] = __builtin_amdgcn_mfma_f32_16x16x32_bf16(a[i], b[j], acc[i][j], 0, 0, 0);
    }
  }

  // ---- Epilogue: acc + bias -> fp32 out
  // C/D layout (16x16x32): col(N)=lane&15, row(M)=(lane>>4)*4+r  [m89/m91]
  const int colbase = n0 + wn + (lane & 15);
  const int rowbase = m0 + wm + ((lane >> 4) << 2);
#pragma unroll
  for (int j = 0; j < 4; ++j) {
    const int col = colbase + j * 16;
    const float bv = Bias[col];
#pragma unroll
    for (int i = 0; i < 4; ++i) {
      const int row = rowbase + i * 16;
#pragma unroll
      for (int r = 0; r < 4; ++r) {
        Out[(size_t)(row + r) * N + col] = acc[i][j][r] + bv;
      }
    }
  }
}

extern "C" void kernel_launch(void* const* d_in, const int* in_sizes, int n_in,
                              void* d_out, int out_size, void* d_ws, size_t ws_size,
                              hipStream_t stream) {
  const float* x    = (const float*)d_in[0];
  const int*   q    = (const int*)d_in[1];
  const float* s    = (const float*)d_in[2];
  const float* z    = (const float*)d_in[3];
  const float* bias = (const float*)d_in[4];
  float*       out  = (float*)d_out;

  const int N  = in_sizes[4];              // 11008
  const int K  = in_sizes[1] / N;          // 4096
  const int M  = in_sizes[0] / K;          // 2048
  const int G  = in_sizes[2] / N;          // 32
  const int GS = K / G;                    // 128

  const int grid = (M / BM) * (N / BN);    // 16 * 86 = 1376
  awq_gemm_kernel<<<grid, NTHREADS, 0, stream>>>(x, q, s, z, bias, out, M, N, K, GS);
}